// Round 2
// baseline (251.616 us; speedup 1.0000x reference)
//
#include <hip/hip_runtime.h>

// Forward kinematics for a serial revolute chain.
// q: [B, L] fp32, axes: [L,3], t_fix: [L,3]  ->  out: [B, L, 4, 4] fp32.
// qd is unused by the reference output.
//
// ROUND 2: 1 THREAD PER ELEMENT (was 4 lanes/element in rounds 0-1).
// Post-mortem of rounds 0/1: two radically different kernels (LDS-staged
// low-occupancy vs direct-store high-occupancy) timed within 4% -- the
// bottleneck is what they SHARED: every 4-lane group computed the same 24
// __sincosf and the same 15-op J-matrix build 4x redundantly, plus
// misaligned per-link LDS constant reads (48B row stride -> scalarized
// ds_read2_b32 + lgkmcnt stall per link).
//
// This version: each thread carries the full 3x3 R + t through the chain.
//  - 24 sincos per element (was 96 lane-calls), J built once (was 4x)
//  - q read exactly once (FETCH 50MB -> 13MB)
//  - s_lnk padded to 64B rows -> exactly 3 broadcast ds_read_b128 per link
//  - per link: 4 global_store_dwordx4 at immediate offsets off one base;
//    consecutive unrolled links complete each 128B line back-to-back so
//    L2 write-combining merges (plain stores, NOT nontemporal, so L2 CAN
//    merge the 64B halves before writeback).
// __launch_bounds__(256,2): cap 256 VGPR -- room for the compiler to
// hoist sincos across links for ILP without spilling (the (256,4)=128
// cap in round 1 was a spill risk with qv[24] + full unroll).

typedef float v4 __attribute__((ext_vector_type(4)));

constexpr int L = 24;

__global__ __launch_bounds__(256, 2) void fk_kernel(
    const float* __restrict__ q,
    const float* __restrict__ axes,
    const float* __restrict__ tfix,
    float* __restrict__ out,
    int nb)
{
    // 12 per-link constants padded to 16 floats (64B rows, all 16B-aligned):
    // {ax,ay,az,fx, fy,fz,xx,yy, zz,xy,xz,yz, pad...}
    __shared__ __align__(16) float s_lnk[L][16];

    if (threadIdx.x < L) {
        const int l = threadIdx.x;
        float ax = axes[l * 3 + 0], ay = axes[l * 3 + 1], az = axes[l * 3 + 2];
        float inv = rsqrtf(ax * ax + ay * ay + az * az);
        ax *= inv; ay *= inv; az *= inv;
        s_lnk[l][0] = ax;              s_lnk[l][1] = ay;              s_lnk[l][2] = az;
        s_lnk[l][3] = tfix[l * 3 + 0]; s_lnk[l][4] = tfix[l * 3 + 1]; s_lnk[l][5] = tfix[l * 3 + 2];
        s_lnk[l][6] = ax * ax;         s_lnk[l][7] = ay * ay;
        s_lnk[l][8] = az * az;         s_lnk[l][9] = ax * ay;
        s_lnk[l][10] = ax * az;        s_lnk[l][11] = ay * az;
        s_lnk[l][12] = 0.f; s_lnk[l][13] = 0.f; s_lnk[l][14] = 0.f; s_lnk[l][15] = 0.f;
    }
    __syncthreads();

    const int b = blockIdx.x * 256 + threadIdx.x;
    if (b >= nb) return;

    // All 24 joint angles for this element: 6 coalesced dwordx4 loads,
    // issued up front so the latency hides under the first links.
    float qv[L];
    {
        const v4* q4 = (const v4*)(q + (size_t)b * L);
        #pragma unroll
        for (int i = 0; i < L / 4; ++i) {
            v4 v = q4[i];
            qv[4 * i + 0] = v.x;
            qv[4 * i + 1] = v.y;
            qv[4 * i + 2] = v.z;
            qv[4 * i + 3] = v.w;
        }
    }

    // Identity pose.
    float R00 = 1.f, R01 = 0.f, R02 = 0.f;
    float R10 = 0.f, R11 = 1.f, R12 = 0.f;
    float R20 = 0.f, R21 = 0.f, R22 = 1.f;
    float tx = 0.f, ty = 0.f, tz = 0.f;

    v4* obase = (v4*)out + (size_t)b * (4 * L);

    #pragma unroll
    for (int l = 0; l < L; ++l) {
        const v4 c0 = *(const v4*)&s_lnk[l][0];
        const v4 c1 = *(const v4*)&s_lnk[l][4];
        const v4 c2 = *(const v4*)&s_lnk[l][8];
        const float ax = c0.x, ay = c0.y, az = c0.z, fx = c0.w;
        const float fy = c1.x, fz = c1.y, xx = c1.z, yy = c1.w;
        const float zz = c2.x, xy = c2.y, xz = c2.z, yz = c2.w;

        float s, c;
        __sincosf(qv[l], &s, &c);
        const float omc = 1.0f - c;

        // Rodrigues for unit axis a: J = c*I + s*K + (1-c) a a^T
        const float J00 = fmaf(omc, xx, c);
        const float J11 = fmaf(omc, yy, c);
        const float J22 = fmaf(omc, zz, c);
        const float oxy = omc * xy, oxz = omc * xz, oyz = omc * yz;
        const float sx = s * ax, sy = s * ay, sz = s * az;
        const float J01 = oxy - sz, J10 = oxy + sz;
        const float J02 = oxz + sy, J20 = oxz - sy;
        const float J12 = oyz - sx, J21 = oyz + sx;

        // translation uses the PARENT rotation (pre-update): t += R @ f
        tx = fmaf(R00, fx, fmaf(R01, fy, fmaf(R02, fz, tx)));
        ty = fmaf(R10, fx, fmaf(R11, fy, fmaf(R12, fz, ty)));
        tz = fmaf(R20, fx, fmaf(R21, fy, fmaf(R22, fz, tz)));

        // R = R @ J
        const float n00 = fmaf(R00, J00, fmaf(R01, J10, R02 * J20));
        const float n01 = fmaf(R00, J01, fmaf(R01, J11, R02 * J21));
        const float n02 = fmaf(R00, J02, fmaf(R01, J12, R02 * J22));
        const float n10 = fmaf(R10, J00, fmaf(R11, J10, R12 * J20));
        const float n11 = fmaf(R10, J01, fmaf(R11, J11, R12 * J21));
        const float n12 = fmaf(R10, J02, fmaf(R11, J12, R12 * J22));
        const float n20 = fmaf(R20, J00, fmaf(R21, J10, R22 * J20));
        const float n21 = fmaf(R20, J01, fmaf(R21, J11, R22 * J21));
        const float n22 = fmaf(R20, J02, fmaf(R21, J12, R22 * J22));
        R00 = n00; R01 = n01; R02 = n02;
        R10 = n10; R11 = n11; R12 = n12;
        R20 = n20; R21 = n21; R22 = n22;

        // out[b][l] = [[R | t], [0 0 0 1]] -- 64B contiguous per link,
        // all four stores at immediate offsets off obase.
        obase[l * 4 + 0] = v4{R00, R01, R02, tx};
        obase[l * 4 + 1] = v4{R10, R11, R12, ty};
        obase[l * 4 + 2] = v4{R20, R21, R22, tz};
        obase[l * 4 + 3] = v4{0.f, 0.f, 0.f, 1.f};
    }
}

extern "C" void kernel_launch(void* const* d_in, const int* in_sizes, int n_in,
                              void* d_out, int out_size, void* d_ws, size_t ws_size,
                              hipStream_t stream) {
    const float* q    = (const float*)d_in[0];
    // d_in[1] = qd: unused by the reference output
    const float* axes = (const float*)d_in[2];
    const float* tfix = (const float*)d_in[3];
    float* out = (float*)d_out;

    const int nb = in_sizes[0] / L;                 // 131072
    const int grid = (nb + 255) / 256;              // 1 thread per element
    fk_kernel<<<grid, 256, 0, stream>>>(q, axes, tfix, out, nb);
}

// Round 3
// 224.022 us; speedup vs baseline: 1.1232x; 1.1232x over previous
//
#include <hip/hip_runtime.h>

// Forward kinematics for a serial revolute chain.
// q: [B, L] fp32, axes: [L,3], t_fix: [L,3]  ->  out: [B, L, 4, 4] fp32.
// qd is unused by the reference output.
//
// ROUND 3: chunked LDS staging + high occupancy.
// Evidence so far: r0 (staged 1KB stores, 1.5 waves/SIMD) = 222us,
// r1 (direct 64B-group stores, high occ) = 214us, r2 (direct 16B-lane
// stores, high occ, 2x LESS VALU) = 252us. Less compute got slower ->
// VALU exonerated; ranking is monotone in per-instruction store
// contiguity. This round takes the unexplored quadrant: 1KB-contiguous
// wave stores AND 4 waves/SIMD.
//
//  - 4 lanes/element, lane owns one output row (row i of R@J depends
//    only on row i of R) -- r1's proven compute structure.
//  - Stage only 8 links at a time: per-wave buffer 16 elem x 8 links x
//    64B (+pad) = 8.4KB; 4 waves -> 35KB/block -> 4 blocks/CU (vs r0's
//    50KB full-chain tile at 3 blocks of 128 = 1.5 waves/SIMD).
//  - Buffers are PER-WAVE private: no __syncthreads in the chain loop.
//    Same-wave ds_write->ds_read ordering = compiler lgkmcnt (addresses
//    may-alias per thread, so it must order; the asm "memory" fence
//    keeps compute/drain phases from interleaving).
//  - Element stride 132 words (132%32==4, r0's 388-trick): ds_write_b128
//    and drain ds_read_b128 both land 8 lanes per 4-bank group = the
//    wave64 minimum, 0 conflicts.
//  - Drain: 8 nontemporal wave-wide dwordx4 stores per chunk, each
//    covering two 512B-contiguous runs (full 128B lines).

typedef float v4 __attribute__((ext_vector_type(4)));

constexpr int L = 24;
constexpr int CHUNK = 8;              // links staged per drain
constexpr int NCHUNK = L / CHUNK;     // 3
constexpr int CW  = CHUNK * 16;       // words per element per chunk (128)
constexpr int CWP = CW + 4;           // padded LDS stride (132)
constexpr int WAVE_WORDS = 16 * CWP;  // 2112 words = 8448 B per wave

__global__ __launch_bounds__(256, 4) void fk_kernel(
    const float* __restrict__ q,
    const float* __restrict__ axes,
    const float* __restrict__ tfix,
    float* __restrict__ out,
    int nb)
{
    __shared__ __align__(16) float s_lnk[L][16];
    __shared__ __align__(16) float s_buf[4 * WAVE_WORDS];   // 33792 B

    const int tid  = threadIdx.x;
    const int wave = tid >> 6;
    const int lane = tid & 63;
    const int e    = lane >> 2;    // element within wave (0..15)
    const int r    = lane & 3;     // output row owned by this lane
    const int wave_elem0 = blockIdx.x * 64 + wave * 16;
    const int b = wave_elem0 + e;

    // Issue q loads BEFORE the barrier so their latency overlaps the
    // s_lnk setup. Redundant across the 4-lane group; L1 broadcast
    // absorbs it (r1 showed this is not the bottleneck).
    float qv[L];
    if (b < nb) {
        const v4* q4 = (const v4*)(q + (size_t)b * L);
        #pragma unroll
        for (int i = 0; i < L / 4; ++i) {
            v4 v = q4[i];
            qv[4*i+0] = v.x; qv[4*i+1] = v.y; qv[4*i+2] = v.z; qv[4*i+3] = v.w;
        }
    }

    if (tid < L) {
        const int l = tid;
        float ax = axes[l*3+0], ay = axes[l*3+1], az = axes[l*3+2];
        float inv = rsqrtf(ax*ax + ay*ay + az*az);
        ax *= inv; ay *= inv; az *= inv;
        s_lnk[l][0] = ax;            s_lnk[l][1] = ay;            s_lnk[l][2] = az;
        s_lnk[l][3] = tfix[l*3+0];   s_lnk[l][4] = tfix[l*3+1];   s_lnk[l][5] = tfix[l*3+2];
        s_lnk[l][6] = ax*ax;         s_lnk[l][7] = ay*ay;
        s_lnk[l][8] = az*az;         s_lnk[l][9] = ax*ay;
        s_lnk[l][10] = ax*az;        s_lnk[l][11] = ay*az;
        s_lnk[l][12] = 0.f; s_lnk[l][13] = 0.f; s_lnk[l][14] = 0.f; s_lnk[l][15] = 0.f;
    }
    __syncthreads();

    // Row r of the identity pose; row 3 -> (0,0,0,1), a fixed point of
    // the recurrence (Ra=Rb=Rc=0).
    float Ra = (r == 0) ? 1.f : 0.f;
    float Rb = (r == 1) ? 1.f : 0.f;
    float Rc = (r == 2) ? 1.f : 0.f;
    float t  = (r == 3) ? 1.f : 0.f;

    float* wbuf = s_buf + wave * WAVE_WORDS;
    v4* lrow = (v4*)(wbuf + e * CWP + r * 4);   // + lc*16 words per link

    #pragma unroll
    for (int chunk = 0; chunk < NCHUNK; ++chunk) {
        if (b < nb) {
            #pragma unroll
            for (int lc = 0; lc < CHUNK; ++lc) {
                const int l = chunk * CHUNK + lc;
                const v4 c0 = *(const v4*)&s_lnk[l][0];
                const v4 c1 = *(const v4*)&s_lnk[l][4];
                const v4 c2 = *(const v4*)&s_lnk[l][8];
                const float ax = c0.x, ay = c0.y, az = c0.z, fx = c0.w;
                const float fy = c1.x, fz = c1.y, xx = c1.z, yy = c1.w;
                const float zz = c2.x, xy = c2.y, xz = c2.z, yz = c2.w;

                float s, c;
                __sincosf(qv[l], &s, &c);
                const float omc = 1.0f - c;

                // Rodrigues for unit axis a: J = c*I + s*K + (1-c) a a^T
                const float J00 = fmaf(omc, xx, c);
                const float J11 = fmaf(omc, yy, c);
                const float J22 = fmaf(omc, zz, c);
                const float oxy = omc * xy, oxz = omc * xz, oyz = omc * yz;
                const float sx = s * ax, sy = s * ay, sz = s * az;
                const float J01 = oxy - sz, J10 = oxy + sz;
                const float J02 = oxz + sy, J20 = oxz - sy;
                const float J12 = oyz - sx, J21 = oyz + sx;

                // translation uses the PARENT rotation row (pre-update)
                t = fmaf(Ra, fx, fmaf(Rb, fy, fmaf(Rc, fz, t)));

                // row r of R_child = row r of R_parent @ J
                const float na  = fmaf(Ra, J00, fmaf(Rb, J10, Rc * J20));
                const float nb_ = fmaf(Ra, J01, fmaf(Rb, J11, Rc * J21));
                const float nc  = fmaf(Ra, J02, fmaf(Rb, J12, Rc * J22));
                Ra = na; Rb = nb_; Rc = nc;

                lrow[lc * 4] = v4{Ra, Rb, Rc, t};
            }
        }

        // Keep the drain's ds_reads ordered after the ds_writes above
        // (they may-alias per-thread; the fence stops phase interleave).
        asm volatile("" ::: "memory");

        // Drain this chunk: 8 wave-wide 16B stores, each covering two
        // 512B-contiguous runs (elements 2j and 2j+1 of this wave).
        float* gbase = out + (size_t)wave_elem0 * 384 + chunk * CW;
        if (wave_elem0 + 15 < nb) {
            #pragma unroll
            for (int j = 0; j < CHUNK; ++j) {
                const unsigned w = j * 256 + lane * 4;   // flat word in [0,2048)
                const unsigned elem = w >> 7;            // 128 words per elem-chunk
                const unsigned rem  = w & 127u;
                v4 v = *(const v4*)(wbuf + elem * CWP + rem);
                __builtin_nontemporal_store(v, (v4*)(gbase + (size_t)elem * 384 + rem));
            }
        } else if (wave_elem0 < nb) {
            #pragma unroll
            for (int j = 0; j < CHUNK; ++j) {
                const unsigned w = j * 256 + lane * 4;
                const unsigned elem = w >> 7;
                const unsigned rem  = w & 127u;
                if (wave_elem0 + (int)elem < nb) {
                    v4 v = *(const v4*)(wbuf + elem * CWP + rem);
                    __builtin_nontemporal_store(v, (v4*)(gbase + (size_t)elem * 384 + rem));
                }
            }
        }
    }
}

extern "C" void kernel_launch(void* const* d_in, const int* in_sizes, int n_in,
                              void* d_out, int out_size, void* d_ws, size_t ws_size,
                              hipStream_t stream) {
    const float* q    = (const float*)d_in[0];
    // d_in[1] = qd: unused by the reference output
    const float* axes = (const float*)d_in[2];
    const float* tfix = (const float*)d_in[3];
    float* out = (float*)d_out;

    const int nb = in_sizes[0] / L;        // 131072
    const int grid = (nb + 63) / 64;       // 64 elements per 256-thread block
    fk_kernel<<<grid, 256, 0, stream>>>(q, axes, tfix, out, nb);
}